// Round 3
// baseline (4309.081 us; speedup 1.0000x reference)
//
#include <hip/hip_runtime.h>
#include <math.h>

#define NPTS   2048
#define BATCH  16
#define EPS    0.0025f                      // blur=0.05, p=2 -> eps = 0.05^2
#define SCALE  577.0780163555853f           // (1/EPS) * log2(e)
#define LN2    0.6931471805599453f
#define LN_N   7.6246189861593985f          // ln(2048)
#define ITERS  50
#define TILES  32                           // blocks per batch
#define NBLK   (BATCH * TILES)              // 512 = 2 blocks/CU exact fit
#define RPT    4                            // rows per thread
#define LPR    16                           // lanes per row
#define RPB    64                           // rows per block
#define NEG_INF (-3.0e38f)
#define LDS_BYTES (2 * NPTS * 16 + 64)      // PT + PP + gsum

__device__ __forceinline__ float exp2fast(float x) { return __builtin_amdgcn_exp2f(x); }
__device__ __forceinline__ float log2fast(float x) { return __builtin_amdgcn_logf(x); }

// Per-batch barrier: unique slot per use (zeroed by memset each launch).
__device__ __forceinline__ void batch_barrier(int* slot, int tid)
{
    __syncthreads();                          // all prior LDS/global work done
    if (tid == 0) {
        __threadfence();                      // release my f/g stores device-wide
        __hip_atomic_fetch_add(slot, 1, __ATOMIC_ACQ_REL, __HIP_MEMORY_SCOPE_AGENT);
        while (__hip_atomic_load(slot, __ATOMIC_ACQUIRE, __HIP_MEMORY_SCOPE_AGENT) < TILES)
            __builtin_amdgcn_s_sleep(2);
        __threadfence();                      // acquire
    }
    __syncthreads();
}

// Online-LSE scan of 4 rows against the staged cloud P (w already holds
// (pot - 0.5*|y|^2)*SCALE). t = dot(x, y*SC) + w; per-row const added later.
__device__ __forceinline__ void lse_scan(const float4* __restrict__ P, int sub,
    const float* x0, const float* x1, const float* x2, float* mx, float* s)
{
    #pragma unroll
    for (int rr = 0; rr < RPT; ++rr) { mx[rr] = NEG_INF; s[rr] = 0.0f; }
    for (int k = sub; k < NPTS; k += 4 * LPR) {
        float4 c0 = P[k], c1 = P[k + LPR], c2 = P[k + 2*LPR], c3 = P[k + 3*LPR];
        #pragma unroll
        for (int rr = 0; rr < RPT; ++rr) {
            float t0 = fmaf(x0[rr], c0.x, fmaf(x1[rr], c0.y, fmaf(x2[rr], c0.z, c0.w)));
            float t1 = fmaf(x0[rr], c1.x, fmaf(x1[rr], c1.y, fmaf(x2[rr], c1.z, c1.w)));
            float t2 = fmaf(x0[rr], c2.x, fmaf(x1[rr], c2.y, fmaf(x2[rr], c2.z, c2.w)));
            float t3 = fmaf(x0[rr], c3.x, fmaf(x1[rr], c3.y, fmaf(x2[rr], c3.z, c3.w)));
            float mc = fmaxf(fmaxf(t0, t1), fmaxf(t2, t3));
            float nm = fmaxf(mx[rr], mc);
            float er = exp2fast(mx[rr] - nm);
            float e0 = exp2fast(t0 - nm);
            float e1 = exp2fast(t1 - nm);
            float e2 = exp2fast(t2 - nm);
            float e3 = exp2fast(t3 - nm);
            s[rr]  = fmaf(s[rr], er, (e0 + e1) + (e2 + e3));
            mx[rr] = nm;
        }
    }
}

__device__ __forceinline__ void lse_merge_store(float* dst, const float* a2c,
    float* mx, float* s, int sub)
{
    #pragma unroll
    for (int d = 1; d < LPR; d <<= 1) {
        #pragma unroll
        for (int rr = 0; rr < RPT; ++rr) {
            float om = __shfl_xor(mx[rr], d);
            float os = __shfl_xor(s[rr],  d);
            float nm = fmaxf(mx[rr], om);
            s[rr]  = fmaf(s[rr], exp2fast(mx[rr] - nm), os * exp2fast(om - nm));
            mx[rr] = nm;
        }
    }
    if (sub == 0) {
        #pragma unroll
        for (int rr = 0; rr < RPT; ++rr) {
            float v = EPS * (LN_N - LN2 * (a2c[rr] + mx[rr] + log2fast(s[rr])));
            __hip_atomic_store(&dst[rr], v, __ATOMIC_RELAXED, __HIP_MEMORY_SCOPE_AGENT);
        }
    }
}

// Chamfer: with pristine w = -0.5*SC*|y|^2, max_m(dot+w) gives
// min d^2 = (-2/SC)*(a2 + max). Returns clamped 4-row sum (valid on sub==0).
__device__ __forceinline__ float cham_scan(const float4* __restrict__ P, int sub,
    const float* x0, const float* x1, const float* x2, const float* a2c)
{
    float m[RPT];
    #pragma unroll
    for (int rr = 0; rr < RPT; ++rr) m[rr] = NEG_INF;
    for (int k = sub; k < NPTS; k += 4 * LPR) {
        float4 c0 = P[k], c1 = P[k + LPR], c2 = P[k + 2*LPR], c3 = P[k + 3*LPR];
        #pragma unroll
        for (int rr = 0; rr < RPT; ++rr) {
            float t0 = fmaf(x0[rr], c0.x, fmaf(x1[rr], c0.y, fmaf(x2[rr], c0.z, c0.w)));
            float t1 = fmaf(x0[rr], c1.x, fmaf(x1[rr], c1.y, fmaf(x2[rr], c1.z, c1.w)));
            float t2 = fmaf(x0[rr], c2.x, fmaf(x1[rr], c2.y, fmaf(x2[rr], c2.z, c2.w)));
            float t3 = fmaf(x0[rr], c3.x, fmaf(x1[rr], c3.y, fmaf(x2[rr], c3.z, c3.w)));
            m[rr] = fmaxf(m[rr], fmaxf(fmaxf(t0, t1), fmaxf(t2, t3)));
        }
    }
    #pragma unroll
    for (int d = 1; d < LPR; d <<= 1) {
        #pragma unroll
        for (int rr = 0; rr < RPT; ++rr) m[rr] = fmaxf(m[rr], __shfl_xor(m[rr], d));
    }
    float sum = 0.0f;
    #pragma unroll
    for (int rr = 0; rr < RPT; ++rr)
        sum += fmaxf((-2.0f / SCALE) * (a2c[rr] + m[rr]), 0.0f);
    return sum;
}

__global__ __launch_bounds__(256, 2) void sink_persist(
    const float* __restrict__ Xtrue, const float* __restrict__ Ypred,
    float* __restrict__ F, float* __restrict__ G,
    float* __restrict__ cham, int* __restrict__ bar)
{
    extern __shared__ char smem[];
    float4* PT   = (float4*)smem;            // true cloud (cols for g-update)
    float4* PP   = PT + NPTS;                // pred cloud (cols for f-update)
    float*  gsum = (float*)(PP + NPTS);      // [16] block-reduce scratch

    const int bid  = blockIdx.x;
    const int b    = bid >> 5;               // batch
    const int tile = bid & (TILES - 1);
    const int tid  = threadIdx.x;
    const int sub  = tid & (LPR - 1);
    const int grp  = tid >> 4;
    const int row0 = tile * RPB + grp * RPT;

    const float* Xb = Xtrue + (size_t)b * NPTS * 3;
    const float* Yb = Ypred + (size_t)b * NPTS * 3;

    // Row points in registers (unscaled) + per-row log2-domain constants
    float tx0[RPT], tx1[RPT], tx2[RPT], ta2[RPT];   // true rows (f-update)
    float px0[RPT], px1[RPT], px2[RPT], pa2[RPT];   // pred rows (g-update)
    #pragma unroll
    for (int rr = 0; rr < RPT; ++rr) {
        const float* p = Xb + 3 * (row0 + rr);
        tx0[rr] = p[0]; tx1[rr] = p[1]; tx2[rr] = p[2];
        ta2[rr] = -0.5f * SCALE * (tx0[rr]*tx0[rr] + tx1[rr]*tx1[rr] + tx2[rr]*tx2[rr]);
        const float* q = Yb + 3 * (row0 + rr);
        px0[rr] = q[0]; px1[rr] = q[1]; px2[rr] = q[2];
        pa2[rr] = -0.5f * SCALE * (px0[rr]*px0[rr] + px1[rr]*px1[rr] + px2[rr]*px2[rr]);
    }

    // Stage both clouds once: scaled coords, w = -0.5*SC*|y|^2  (pot = 0)
    for (int m = tid; m < NPTS; m += 256) {
        float a0 = Xb[3*m], a1 = Xb[3*m+1], a2_ = Xb[3*m+2];
        PT[m] = make_float4(a0*SCALE, a1*SCALE, a2_*SCALE,
                            -0.5f*SCALE*(a0*a0 + a1*a1 + a2_*a2_));
        float c0 = Yb[3*m], c1 = Yb[3*m+1], c2_ = Yb[3*m+2];
        PP[m] = make_float4(c0*SCALE, c1*SCALE, c2_*SCALE,
                            -0.5f*SCALE*(c0*c0 + c1*c1 + c2_*c2_));
    }
    __syncthreads();

    // ---- Chamfer, both directions (w still pristine) ----
    {
        float sA = cham_scan(PP, sub, tx0, tx1, tx2, ta2);
        if (sub == 0) gsum[grp] = sA;
        __syncthreads();
        if (tid == 0) {
            float t = 0.0f;
            #pragma unroll
            for (int i = 0; i < 16; ++i) t += gsum[i];
            cham[bid] = t;
        }
        __syncthreads();
        float sB = cham_scan(PT, sub, px0, px1, px2, pa2);
        if (sub == 0) gsum[grp] = sB;
        __syncthreads();
        if (tid == 0) {
            float t = 0.0f;
            #pragma unroll
            for (int i = 0; i < 16; ++i) t += gsum[i];
            cham[NBLK + bid] = t;
        }
    }

    float* Fb = F + (size_t)b * NPTS;
    float* Gb = G + (size_t)b * NPTS;

    // ---- Sinkhorn: 50 iterations, geometry stays in LDS ----
    for (int it = 0; it < ITERS; ++it) {
        if (it > 0) {
            // refresh PP.w from g (recompute -0.5*SC*yy from scaled coords)
            for (int m = tid; m < NPTS; m += 256) {
                float g = __hip_atomic_load(&Gb[m], __ATOMIC_RELAXED, __HIP_MEMORY_SCOPE_AGENT);
                float4 c = PP[m];
                PP[m].w = fmaf(g, SCALE, (-0.5f/SCALE) * (c.x*c.x + c.y*c.y + c.z*c.z));
            }
        }
        __syncthreads();

        float mx[RPT], s[RPT];
        lse_scan(PP, sub, tx0, tx1, tx2, mx, s);         // f-update
        lse_merge_store(Fb + row0, ta2, mx, s, sub);
        batch_barrier(&bar[(2*it) * BATCH + b], tid);

        // refresh PT.w from f
        for (int m = tid; m < NPTS; m += 256) {
            float f = __hip_atomic_load(&Fb[m], __ATOMIC_RELAXED, __HIP_MEMORY_SCOPE_AGENT);
            float4 c = PT[m];
            PT[m].w = fmaf(f, SCALE, (-0.5f/SCALE) * (c.x*c.x + c.y*c.y + c.z*c.z));
        }
        __syncthreads();

        lse_scan(PT, sub, px0, px1, px2, mx, s);         // g-update
        lse_merge_store(Gb + row0, pa2, mx, s, sub);
        if (it < ITERS - 1)
            batch_barrier(&bar[(2*it + 1) * BATCH + b], tid);
    }
}

__global__ void finalize(const float* __restrict__ F, const float* __restrict__ G,
                         const float* __restrict__ cham, float* __restrict__ out)
{
    const int b = blockIdx.x, tid = threadIdx.x;
    float sf = 0.0f, sg = 0.0f, sc = 0.0f;
    for (int i = tid; i < NPTS; i += 256) {
        sf += F[(size_t)b * NPTS + i];
        sg += G[(size_t)b * NPTS + i];
    }
    for (int i = tid; i < 2 * NBLK; i += 256) sc += cham[i];
    #pragma unroll
    for (int d = 1; d < 64; d <<= 1) {
        sf += __shfl_xor(sf, d); sg += __shfl_xor(sg, d); sc += __shfl_xor(sc, d);
    }
    __shared__ float wf[4], wg[4], wc[4];
    const int w = tid >> 6;
    if ((tid & 63) == 0) { wf[w] = sf; wg[w] = sg; wc[w] = sc; }
    __syncthreads();
    if (tid == 0) {
        float tf = wf[0] + wf[1] + wf[2] + wf[3];
        float tg = wg[0] + wg[1] + wg[2] + wg[3];
        float tc = wc[0] + wc[1] + wc[2] + wc[3];
        float emd = (tf + tg) * (1.0f / NPTS);
        float cd  = tc * (1.0f / (BATCH * NPTS));
        out[b] = 0.5f * cd + 0.5f * emd;
    }
}

extern "C" void kernel_launch(void* const* d_in, const int* in_sizes, int n_in,
                              void* d_out, int out_size, void* d_ws, size_t ws_size,
                              hipStream_t stream)
{
    const float* Xtrue = (const float*)d_in[0];   // y_true: rows of D
    const float* Ypred = (const float*)d_in[1];   // y_pred: cols of D
    float* F    = (float*)d_ws;                   // [16][2048]
    float* G    = F + BATCH * NPTS;               // [16][2048]
    float* cham = G + BATCH * NPTS;               // [2 * NBLK]
    int*   bar  = (int*)(cham + 2 * NBLK);        // [100][16] barrier slots

    hipMemsetAsync(bar, 0, 100 * BATCH * sizeof(int), stream);

    void* args[] = { (void*)&Xtrue, (void*)&Ypred, (void*)&F, (void*)&G,
                     (void*)&cham, (void*)&bar };
    hipError_t e = hipLaunchCooperativeKernel((const void*)sink_persist,
                                              dim3(NBLK), dim3(256),
                                              args, LDS_BYTES, stream);
    if (e != hipSuccess) {
        // 512 blocks * (64KB+64B) LDS = exact 2/CU fit -> co-resident anyway
        sink_persist<<<dim3(NBLK), dim3(256), LDS_BYTES, stream>>>(
            Xtrue, Ypred, F, G, cham, bar);
    }

    finalize<<<dim3(BATCH), dim3(256), 0, stream>>>(F, G, cham, (float*)d_out);
}

// Round 4
// 1965.138 us; speedup vs baseline: 2.1928x; 2.1928x over previous
//
#include <hip/hip_runtime.h>
#include <math.h>

#define NPTS   2048
#define BATCH  16
#define EPS    0.0025f                      // blur=0.05, p=2 -> eps = 0.05^2
#define SCALE  577.0780163555853f           // (1/EPS) * log2(e)
#define INV_SCALE (1.0f / SCALE)
#define LN2    0.6931471805599453f
#define LN_N   7.6246189861593985f          // ln(2048)
#define ITERS  50

#define RPT    4                            // rows per thread
#define LPR    32                           // lanes per row
#define RPB    32                           // rows per block (256/LPR*RPT)
#define GRID_X (NPTS / RPB)                 // 64 -> 1024 blocks = 4/CU
#define NEG_INF (-3.0e38f)

__device__ __forceinline__ float exp2fast(float x) { return __builtin_amdgcn_exp2f(x); }
__device__ __forceinline__ float log2fast(float x) { return __builtin_amdgcn_logf(x); }

// Pack each point once: (x*SC, y*SC, z*SC, -0.5*|p|^2*SC).
__global__ __launch_bounds__(256) void pack_geo(
    const float* __restrict__ X, const float* __restrict__ Y,
    float4* __restrict__ Xg, float4* __restrict__ Yg)
{
    const int b = blockIdx.y;
    const int m = blockIdx.x * 256 + threadIdx.x;
    const float* xb = X + (size_t)b * NPTS * 3;
    const float* yb = Y + (size_t)b * NPTS * 3;
    float a0 = xb[3*m], a1 = xb[3*m+1], a2 = xb[3*m+2];
    Xg[(size_t)b * NPTS + m] = make_float4(a0*SCALE, a1*SCALE, a2*SCALE,
                                           -0.5f*SCALE*(a0*a0 + a1*a1 + a2*a2));
    float c0 = yb[3*m], c1 = yb[3*m+1], c2 = yb[3*m+2];
    Yg[(size_t)b * NPTS + m] = make_float4(c0*SCALE, c1*SCALE, c2*SCALE,
                                           -0.5f*SCALE*(c0*c0 + c1*c1 + c2*c2));
}

// One Sinkhorn half-update. Rows from geoR (coords unscaled on load, a2 = .w),
// cols staged to LDS with potential folded: w = geo.w + Pin*SCALE.
// Pin == nullptr means potential == 0 (first iteration).
__global__ __launch_bounds__(256, 4) void sink_update(
    const float4* __restrict__ geoR, const float4* __restrict__ geoC,
    const float* __restrict__ Pin, float* __restrict__ Pout)
{
    __shared__ float4 P[NPTS];
    const int b    = blockIdx.y;
    const int tile = blockIdx.x;
    const int tid  = threadIdx.x;
    const int sub  = tid & (LPR - 1);
    const int grp  = tid >> 5;               // 8 row-groups
    const int row0 = tile * RPB + grp * RPT;

    // row registers (issue loads early; L2-resident)
    const float4* gR = geoR + (size_t)b * NPTS + row0;
    float x0[RPT], x1[RPT], x2[RPT], a2[RPT], mx[RPT], s[RPT];
    #pragma unroll
    for (int rr = 0; rr < RPT; ++rr) {
        float4 r = gR[rr];
        x0[rr] = r.x * INV_SCALE;            // unscale: cols carry the SCALE
        x1[rr] = r.y * INV_SCALE;
        x2[rr] = r.z * INV_SCALE;
        a2[rr] = r.w;                        // -0.5*|x|^2*SCALE
        mx[rr] = NEG_INF; s[rr] = 0.0f;
    }

    // stage cols: pure b128 copy + one fma folding the potential
    const float4* gC = geoC + (size_t)b * NPTS;
    if (Pin) {
        const float* pb = Pin + (size_t)b * NPTS;
        for (int m = tid; m < NPTS; m += 256) {
            float4 c = gC[m];
            c.w = fmaf(pb[m], SCALE, c.w);
            P[m] = c;
        }
    } else {
        for (int m = tid; m < NPTS; m += 256) P[m] = gC[m];
    }
    __syncthreads();

    // online-LSE, 4-column chunks (5 exps / 4 cols / row)
    for (int k = sub; k < NPTS; k += 4 * LPR) {
        float4 c0 = P[k], c1 = P[k + LPR], c2 = P[k + 2*LPR], c3 = P[k + 3*LPR];
        #pragma unroll
        for (int rr = 0; rr < RPT; ++rr) {
            float t0 = fmaf(x0[rr], c0.x, fmaf(x1[rr], c0.y, fmaf(x2[rr], c0.z, c0.w)));
            float t1 = fmaf(x0[rr], c1.x, fmaf(x1[rr], c1.y, fmaf(x2[rr], c1.z, c1.w)));
            float t2 = fmaf(x0[rr], c2.x, fmaf(x1[rr], c2.y, fmaf(x2[rr], c2.z, c2.w)));
            float t3 = fmaf(x0[rr], c3.x, fmaf(x1[rr], c3.y, fmaf(x2[rr], c3.z, c3.w)));
            float mc = fmaxf(fmaxf(t0, t1), fmaxf(t2, t3));
            float nm = fmaxf(mx[rr], mc);
            float er = exp2fast(mx[rr] - nm);
            float e0 = exp2fast(t0 - nm);
            float e1 = exp2fast(t1 - nm);
            float e2 = exp2fast(t2 - nm);
            float e3 = exp2fast(t3 - nm);
            s[rr]  = fmaf(s[rr], er, (e0 + e1) + (e2 + e3));
            mx[rr] = nm;
        }
    }

    // merge across 32 cooperating lanes
    #pragma unroll
    for (int d = 1; d < LPR; d <<= 1) {
        #pragma unroll
        for (int rr = 0; rr < RPT; ++rr) {
            float om = __shfl_xor(mx[rr], d);
            float os = __shfl_xor(s[rr],  d);
            float nm = fmaxf(mx[rr], om);
            s[rr]  = fmaf(s[rr], exp2fast(mx[rr] - nm), os * exp2fast(om - nm));
            mx[rr] = nm;
        }
    }
    if (sub == 0) {
        float* dst = Pout + (size_t)b * NPTS + row0;
        #pragma unroll
        for (int rr = 0; rr < RPT; ++rr) {
            float lse2 = a2[rr] + mx[rr] + log2fast(s[rr]);
            dst[rr] = EPS * (LN_N - LN2 * lse2);
        }
    }
}

// Chamfer direction from packed geometry (pristine w):
// min_m d^2 = (-2/SCALE) * (a2 + max_m(dot + w)), clamped at 0.
__global__ __launch_bounds__(256, 4) void chamfer_min(
    const float4* __restrict__ geoR, const float4* __restrict__ geoC,
    float* __restrict__ part)
{
    __shared__ float4 P[NPTS];
    __shared__ float gsum[8];
    const int b = blockIdx.y, tile = blockIdx.x, tid = threadIdx.x;
    const int sub = tid & (LPR - 1);
    const int grp = tid >> 5;
    const int row0 = tile * RPB + grp * RPT;

    const float4* gR = geoR + (size_t)b * NPTS + row0;
    float x0[RPT], x1[RPT], x2[RPT], a2[RPT], m[RPT];
    #pragma unroll
    for (int rr = 0; rr < RPT; ++rr) {
        float4 r = gR[rr];
        x0[rr] = r.x * INV_SCALE; x1[rr] = r.y * INV_SCALE; x2[rr] = r.z * INV_SCALE;
        a2[rr] = r.w; m[rr] = NEG_INF;
    }
    const float4* gC = geoC + (size_t)b * NPTS;
    for (int mm = tid; mm < NPTS; mm += 256) P[mm] = gC[mm];
    __syncthreads();

    for (int k = sub; k < NPTS; k += 4 * LPR) {
        float4 c0 = P[k], c1 = P[k + LPR], c2 = P[k + 2*LPR], c3 = P[k + 3*LPR];
        #pragma unroll
        for (int rr = 0; rr < RPT; ++rr) {
            float t0 = fmaf(x0[rr], c0.x, fmaf(x1[rr], c0.y, fmaf(x2[rr], c0.z, c0.w)));
            float t1 = fmaf(x0[rr], c1.x, fmaf(x1[rr], c1.y, fmaf(x2[rr], c1.z, c1.w)));
            float t2 = fmaf(x0[rr], c2.x, fmaf(x1[rr], c2.y, fmaf(x2[rr], c2.z, c2.w)));
            float t3 = fmaf(x0[rr], c3.x, fmaf(x1[rr], c3.y, fmaf(x2[rr], c3.z, c3.w)));
            m[rr] = fmaxf(m[rr], fmaxf(fmaxf(t0, t1), fmaxf(t2, t3)));
        }
    }
    #pragma unroll
    for (int d = 1; d < LPR; d <<= 1) {
        #pragma unroll
        for (int rr = 0; rr < RPT; ++rr) m[rr] = fmaxf(m[rr], __shfl_xor(m[rr], d));
    }
    if (sub == 0) {
        float sum = 0.0f;
        #pragma unroll
        for (int rr = 0; rr < RPT; ++rr)
            sum += fmaxf((-2.0f * INV_SCALE) * (a2[rr] + m[rr]), 0.0f);
        gsum[grp] = sum;
    }
    __syncthreads();
    if (tid == 0) {
        float t = 0.0f;
        #pragma unroll
        for (int i = 0; i < 8; ++i) t += gsum[i];
        part[blockIdx.y * GRID_X + blockIdx.x] = t;
    }
}

__global__ void finalize(const float* __restrict__ F, const float* __restrict__ G,
                         const float* __restrict__ part, float* __restrict__ out)
{
    const int b = blockIdx.x, tid = threadIdx.x;
    float sf = 0.0f, sg = 0.0f, sc = 0.0f;
    for (int i = tid; i < NPTS; i += 256) {
        sf += F[(size_t)b * NPTS + i];
        sg += G[(size_t)b * NPTS + i];
    }
    for (int i = tid; i < 2 * GRID_X * BATCH; i += 256) sc += part[i];
    #pragma unroll
    for (int d = 1; d < 64; d <<= 1) {
        sf += __shfl_xor(sf, d); sg += __shfl_xor(sg, d); sc += __shfl_xor(sc, d);
    }
    __shared__ float wf[4], wg[4], wc[4];
    const int w = tid >> 6;
    if ((tid & 63) == 0) { wf[w] = sf; wg[w] = sg; wc[w] = sc; }
    __syncthreads();
    if (tid == 0) {
        float tf = wf[0] + wf[1] + wf[2] + wf[3];
        float tg = wg[0] + wg[1] + wg[2] + wg[3];
        float tc = wc[0] + wc[1] + wc[2] + wc[3];
        float emd = (tf + tg) * (1.0f / NPTS);
        float cd  = tc * (1.0f / (BATCH * NPTS));
        out[b] = 0.5f * cd + 0.5f * emd;
    }
}

extern "C" void kernel_launch(void* const* d_in, const int* in_sizes, int n_in,
                              void* d_out, int out_size, void* d_ws, size_t ws_size,
                              hipStream_t stream)
{
    const float* Xtrue = (const float*)d_in[0];   // y_true: rows of D
    const float* Ypred = (const float*)d_in[1];   // y_pred: cols of D

    float*  F    = (float*)d_ws;                  // [16][2048]
    float*  G    = F + BATCH * NPTS;              // [16][2048]
    float*  part = G + BATCH * NPTS;              // [2 * 64 * 16]
    float4* Xg   = (float4*)(part + 2 * GRID_X * BATCH + 32);  // padded, 16B-aligned
    float4* Yg   = Xg + BATCH * NPTS;

    pack_geo<<<dim3(NPTS/256, BATCH), dim3(256), 0, stream>>>(Xtrue, Ypred, Xg, Yg);

    dim3 grid(GRID_X, BATCH), blk(256);
    chamfer_min<<<grid, blk, 0, stream>>>(Xg, Yg, part);
    chamfer_min<<<grid, blk, 0, stream>>>(Yg, Xg, part + GRID_X * BATCH);

    // iteration 0: g == 0 handled by nullptr
    sink_update<<<grid, blk, 0, stream>>>(Xg, Yg, nullptr, F);
    sink_update<<<grid, blk, 0, stream>>>(Yg, Xg, F, G);
    for (int it = 1; it < ITERS; ++it) {
        sink_update<<<grid, blk, 0, stream>>>(Xg, Yg, G, F);  // f from g
        sink_update<<<grid, blk, 0, stream>>>(Yg, Xg, F, G);  // g from f
    }
    finalize<<<dim3(BATCH), blk, 0, stream>>>(F, G, part, (float*)d_out);
}

// Round 5
// 1582.321 us; speedup vs baseline: 2.7233x; 1.2419x over previous
//
#include <hip/hip_runtime.h>
#include <math.h>

typedef float v2f __attribute__((ext_vector_type(2)));
typedef float v4f __attribute__((ext_vector_type(4)));

#define NPTS   2048
#define NPAIR  1024
#define BATCH  16
#define EPS    0.0025f                      // blur=0.05, p=2 -> eps = 0.05^2
#define SCALE  577.0780163555853f           // (1/EPS) * log2(e)
#define INV_SCALE (1.0f / SCALE)
#define LN2    0.6931471805599453f
#define LN_N   7.6246189861593985f          // ln(2048)
#define ITERS  50
#define RPT    4                            // rows per thread
#define LPR    32                           // lanes per row
#define RPB    32                           // rows per block
#define GRID_X (NPTS / RPB)                 // 64 -> 1024 blocks = 4/CU
#define NEG_INF (-3.0e38f)

__device__ __forceinline__ float exp2fast(float x) { return __builtin_amdgcn_exp2f(x); }
__device__ __forceinline__ float log2fast(float x) { return __builtin_amdgcn_logf(x); }
__device__ __forceinline__ v2f bc2(float v) { v2f r; r.x = v; r.y = v; return r; }
__device__ __forceinline__ v2f vmax2(v2f a, v2f b) { return __builtin_elementwise_max(a, b); }

// Async global->LDS staging of 2048 v4f (32 KB), linear, wave-uniform LDS base.
__device__ __forceinline__ void stage_async(const v4f* __restrict__ src, v4f* dst, int tid)
{
    const int lane = tid & 63;
    const int wid  = tid >> 6;
    #pragma unroll
    for (int i = 0; i < 8; ++i) {
        const int m0 = i * 256 + wid * 64;
        __builtin_amdgcn_global_load_lds(
            (const __attribute__((address_space(1))) void*)(src + m0 + lane),
            (__attribute__((address_space(3))) void*)(dst + m0), 16, 0, 0);
    }
}

// Pack pair-interleaved geometry:
// PX[p]       = (x_e, x_o, y_e, y_o) * SCALE       (e = point 2p, o = 2p+1)
// PZ[p]=[1024+p] = (z_e, z_o, w_e, w_o), w = -0.5*SCALE*|p|^2
__global__ __launch_bounds__(256) void pack_geo(
    const float* __restrict__ X, const float* __restrict__ Y,
    v4f* __restrict__ Xg, v4f* __restrict__ Yg)
{
    const int b = blockIdx.y;
    const int p = blockIdx.x * 256 + threadIdx.x;
    {
        const float* s = X + (size_t)b * NPTS * 3 + 6 * p;
        float a0=s[0],a1=s[1],a2=s[2],a3=s[3],a4=s[4],a5=s[5];
        float we = -0.5f*SCALE*(a0*a0+a1*a1+a2*a2);
        float wo = -0.5f*SCALE*(a3*a3+a4*a4+a5*a5);
        v4f* d = Xg + (size_t)b * NPTS;
        v4f u; u.x=a0*SCALE; u.y=a3*SCALE; u.z=a1*SCALE; u.w=a4*SCALE; d[p] = u;
        v4f v; v.x=a2*SCALE; v.y=a5*SCALE; v.z=we; v.w=wo; d[NPAIR+p] = v;
    }
    {
        const float* s = Y + (size_t)b * NPTS * 3 + 6 * p;
        float a0=s[0],a1=s[1],a2=s[2],a3=s[3],a4=s[4],a5=s[5];
        float we = -0.5f*SCALE*(a0*a0+a1*a1+a2*a2);
        float wo = -0.5f*SCALE*(a3*a3+a4*a4+a5*a5);
        v4f* d = Yg + (size_t)b * NPTS;
        v4f u; u.x=a0*SCALE; u.y=a3*SCALE; u.z=a1*SCALE; u.w=a4*SCALE; d[p] = u;
        v4f v; v.x=a2*SCALE; v.y=a5*SCALE; v.z=we; v.w=wo; d[NPAIR+p] = v;
    }
}

// One Sinkhorn half-update. Rows from pristine geoR; cols staged (async DMA)
// from stageSrc whose .w already folds the current potential. Writes plain
// potential Pout AND FoldOut = rows' geometry with the NEW potential folded
// (the next dispatch's staging source). partA != nullptr (first f-update,
// pristine cols): also emit chamfer dir-A partial sums from the running max.
__global__ __launch_bounds__(256, 4) void sink_step(
    const v4f* __restrict__ geoR, const v4f* __restrict__ stageSrc,
    float* __restrict__ Pout, v4f* __restrict__ FoldOut, float* __restrict__ partA)
{
    __shared__ v4f S[2 * NPAIR];
    __shared__ float gsum[8];
    v4f* PX = S;
    v4f* PZ = S + NPAIR;

    const int b = blockIdx.y, tile = blockIdx.x, tid = threadIdx.x;
    const int sub = tid & (LPR - 1);
    const int grp = tid >> 5;
    const int row0 = tile * RPB + grp * RPT;

    stage_async(stageSrc + (size_t)b * NPTS, S, tid);

    // rows (pristine, pair-packed): pair q holds rows 2q,2q+1
    const v4f* gR = geoR + (size_t)b * NPTS;
    const int q = row0 >> 1;
    v4f A = gR[q], B = gR[NPAIR + q], C = gR[q + 1], D = gR[NPAIR + q + 1];
    v2f xb[RPT], yb[RPT], zb[RPT];
    float a2[RPT], mx[RPT], s[RPT];
    xb[0]=bc2(A.x*INV_SCALE); yb[0]=bc2(A.z*INV_SCALE); zb[0]=bc2(B.x*INV_SCALE); a2[0]=B.z;
    xb[1]=bc2(A.y*INV_SCALE); yb[1]=bc2(A.w*INV_SCALE); zb[1]=bc2(B.y*INV_SCALE); a2[1]=B.w;
    xb[2]=bc2(C.x*INV_SCALE); yb[2]=bc2(C.z*INV_SCALE); zb[2]=bc2(D.x*INV_SCALE); a2[2]=D.z;
    xb[3]=bc2(C.y*INV_SCALE); yb[3]=bc2(C.w*INV_SCALE); zb[3]=bc2(D.y*INV_SCALE); a2[3]=D.w;
    #pragma unroll
    for (int rr = 0; rr < RPT; ++rr) { mx[rr] = NEG_INF; s[rr] = 0.0f; }

    asm volatile("s_waitcnt vmcnt(0)" ::: "memory");
    __syncthreads();

    // online-LSE over 4 column-pairs (8 cols) per iteration, packed math
    #pragma unroll 2
    for (int k = sub; k < NPAIR; k += 4 * LPR) {
        v4f A0 = PX[k],         Z0 = PZ[k];
        v4f A1 = PX[k + LPR],   Z1 = PZ[k + LPR];
        v4f A2 = PX[k + 2*LPR], Z2 = PZ[k + 2*LPR];
        v4f A3 = PX[k + 3*LPR], Z3 = PZ[k + 3*LPR];
        #pragma unroll
        for (int rr = 0; rr < RPT; ++rr) {
            v2f t0 = xb[rr]*A0.xy + yb[rr]*A0.zw + zb[rr]*Z0.xy + Z0.zw;
            v2f t1 = xb[rr]*A1.xy + yb[rr]*A1.zw + zb[rr]*Z1.xy + Z1.zw;
            v2f t2 = xb[rr]*A2.xy + yb[rr]*A2.zw + zb[rr]*Z2.xy + Z2.zw;
            v2f t3 = xb[rr]*A3.xy + yb[rr]*A3.zw + zb[rr]*Z3.xy + Z3.zw;
            v2f cm = vmax2(vmax2(t0, t1), vmax2(t2, t3));
            float mc = fmaxf(cm.x, cm.y);
            float nm = fmaxf(mx[rr], mc);
            float er = exp2fast(mx[rr] - nm);
            v2f nm2 = bc2(nm);
            v2f u0 = t0 - nm2, u1 = t1 - nm2, u2 = t2 - nm2, u3 = t3 - nm2;
            float e0 = exp2fast(u0.x), e1 = exp2fast(u0.y);
            float e2 = exp2fast(u1.x), e3 = exp2fast(u1.y);
            float e4 = exp2fast(u2.x), e5 = exp2fast(u2.y);
            float e6 = exp2fast(u3.x), e7 = exp2fast(u3.y);
            s[rr]  = fmaf(s[rr], er, ((e0+e1)+(e2+e3)) + ((e4+e5)+(e6+e7)));
            mx[rr] = nm;
        }
    }

    // two-phase merge across 32 lanes: max-reduce, one rescale, sum-reduce
    float om[RPT];
    #pragma unroll
    for (int rr = 0; rr < RPT; ++rr) om[rr] = mx[rr];
    #pragma unroll
    for (int d = 1; d < LPR; d <<= 1) {
        #pragma unroll
        for (int rr = 0; rr < RPT; ++rr) mx[rr] = fmaxf(mx[rr], __shfl_xor(mx[rr], d));
    }
    #pragma unroll
    for (int rr = 0; rr < RPT; ++rr) s[rr] *= exp2fast(om[rr] - mx[rr]);
    #pragma unroll
    for (int d = 1; d < LPR; d <<= 1) {
        #pragma unroll
        for (int rr = 0; rr < RPT; ++rr) s[rr] += __shfl_xor(s[rr], d);
    }

    if (sub == 0) {
        float pot[RPT];
        #pragma unroll
        for (int rr = 0; rr < RPT; ++rr)
            pot[rr] = EPS * (LN_N - LN2 * (a2[rr] + mx[rr] + log2fast(s[rr])));
        float* dp = Pout + (size_t)b * NPTS + row0;
        dp[0] = pot[0]; dp[1] = pot[1]; dp[2] = pot[2]; dp[3] = pot[3];

        // fold-forward: rows' geometry + new potential (next staging source)
        v4f* fo = FoldOut + (size_t)b * NPTS;
        v4f u;
        u.x = xb[0].x*SCALE; u.y = xb[1].x*SCALE; u.z = yb[0].x*SCALE; u.w = yb[1].x*SCALE;
        fo[q] = u;
        u.x = zb[0].x*SCALE; u.y = zb[1].x*SCALE;
        u.z = fmaf(pot[0], SCALE, a2[0]); u.w = fmaf(pot[1], SCALE, a2[1]);
        fo[NPAIR + q] = u;
        u.x = xb[2].x*SCALE; u.y = xb[3].x*SCALE; u.z = yb[2].x*SCALE; u.w = yb[3].x*SCALE;
        fo[q + 1] = u;
        u.x = zb[2].x*SCALE; u.y = zb[3].x*SCALE;
        u.z = fmaf(pot[2], SCALE, a2[2]); u.w = fmaf(pot[3], SCALE, a2[3]);
        fo[NPAIR + q + 1] = u;

        if (partA) {
            float c = 0.0f;
            #pragma unroll
            for (int rr = 0; rr < RPT; ++rr)
                c += fmaxf(-2.0f * INV_SCALE * (a2[rr] + mx[rr]), 0.0f);
            gsum[grp] = c;
        }
    }
    if (partA) {
        __syncthreads();
        if (tid == 0) {
            float t = 0.0f;
            #pragma unroll
            for (int i = 0; i < 8; ++i) t += gsum[i];
            partA[b * GRID_X + tile] = t;
        }
    }
}

// Chamfer dir-B: rows = Y pristine, cols = X pristine. Max-only scan.
__global__ __launch_bounds__(256, 4) void chamfer_b(
    const v4f* __restrict__ geoR, const v4f* __restrict__ stageSrc,
    float* __restrict__ part)
{
    __shared__ v4f S[2 * NPAIR];
    __shared__ float gsum[8];
    v4f* PX = S;
    v4f* PZ = S + NPAIR;
    const int b = blockIdx.y, tile = blockIdx.x, tid = threadIdx.x;
    const int sub = tid & (LPR - 1);
    const int grp = tid >> 5;
    const int row0 = tile * RPB + grp * RPT;

    stage_async(stageSrc + (size_t)b * NPTS, S, tid);

    const v4f* gR = geoR + (size_t)b * NPTS;
    const int q = row0 >> 1;
    v4f A = gR[q], B = gR[NPAIR + q], C = gR[q + 1], D = gR[NPAIR + q + 1];
    v2f xb[RPT], yb[RPT], zb[RPT];
    float a2[RPT], mx[RPT];
    xb[0]=bc2(A.x*INV_SCALE); yb[0]=bc2(A.z*INV_SCALE); zb[0]=bc2(B.x*INV_SCALE); a2[0]=B.z;
    xb[1]=bc2(A.y*INV_SCALE); yb[1]=bc2(A.w*INV_SCALE); zb[1]=bc2(B.y*INV_SCALE); a2[1]=B.w;
    xb[2]=bc2(C.x*INV_SCALE); yb[2]=bc2(C.z*INV_SCALE); zb[2]=bc2(D.x*INV_SCALE); a2[2]=D.z;
    xb[3]=bc2(C.y*INV_SCALE); yb[3]=bc2(C.w*INV_SCALE); zb[3]=bc2(D.y*INV_SCALE); a2[3]=D.w;
    #pragma unroll
    for (int rr = 0; rr < RPT; ++rr) mx[rr] = NEG_INF;

    asm volatile("s_waitcnt vmcnt(0)" ::: "memory");
    __syncthreads();

    #pragma unroll 2
    for (int k = sub; k < NPAIR; k += 4 * LPR) {
        v4f A0 = PX[k],         Z0 = PZ[k];
        v4f A1 = PX[k + LPR],   Z1 = PZ[k + LPR];
        v4f A2 = PX[k + 2*LPR], Z2 = PZ[k + 2*LPR];
        v4f A3 = PX[k + 3*LPR], Z3 = PZ[k + 3*LPR];
        #pragma unroll
        for (int rr = 0; rr < RPT; ++rr) {
            v2f t0 = xb[rr]*A0.xy + yb[rr]*A0.zw + zb[rr]*Z0.xy + Z0.zw;
            v2f t1 = xb[rr]*A1.xy + yb[rr]*A1.zw + zb[rr]*Z1.xy + Z1.zw;
            v2f t2 = xb[rr]*A2.xy + yb[rr]*A2.zw + zb[rr]*Z2.xy + Z2.zw;
            v2f t3 = xb[rr]*A3.xy + yb[rr]*A3.zw + zb[rr]*Z3.xy + Z3.zw;
            v2f cm = vmax2(vmax2(t0, t1), vmax2(t2, t3));
            mx[rr] = fmaxf(mx[rr], fmaxf(cm.x, cm.y));
        }
    }
    #pragma unroll
    for (int d = 1; d < LPR; d <<= 1) {
        #pragma unroll
        for (int rr = 0; rr < RPT; ++rr) mx[rr] = fmaxf(mx[rr], __shfl_xor(mx[rr], d));
    }
    if (sub == 0) {
        float c = 0.0f;
        #pragma unroll
        for (int rr = 0; rr < RPT; ++rr)
            c += fmaxf(-2.0f * INV_SCALE * (a2[rr] + mx[rr]), 0.0f);
        gsum[grp] = c;
    }
    __syncthreads();
    if (tid == 0) {
        float t = 0.0f;
        #pragma unroll
        for (int i = 0; i < 8; ++i) t += gsum[i];
        part[b * GRID_X + tile] = t;
    }
}

__global__ void finalize(const float* __restrict__ F, const float* __restrict__ G,
                         const float* __restrict__ part, float* __restrict__ out)
{
    const int b = blockIdx.x, tid = threadIdx.x;
    float sf = 0.0f, sg = 0.0f, sc = 0.0f;
    for (int i = tid; i < NPTS; i += 256) {
        sf += F[(size_t)b * NPTS + i];
        sg += G[(size_t)b * NPTS + i];
    }
    for (int i = tid; i < 2 * GRID_X * BATCH; i += 256) sc += part[i];
    #pragma unroll
    for (int d = 1; d < 64; d <<= 1) {
        sf += __shfl_xor(sf, d); sg += __shfl_xor(sg, d); sc += __shfl_xor(sc, d);
    }
    __shared__ float wf[4], wg[4], wc[4];
    const int w = tid >> 6;
    if ((tid & 63) == 0) { wf[w] = sf; wg[w] = sg; wc[w] = sc; }
    __syncthreads();
    if (tid == 0) {
        float tf = wf[0] + wf[1] + wf[2] + wf[3];
        float tg = wg[0] + wg[1] + wg[2] + wg[3];
        float tc = wc[0] + wc[1] + wc[2] + wc[3];
        float emd = (tf + tg) * (1.0f / NPTS);
        float cd  = tc * (1.0f / (BATCH * NPTS));
        out[b] = 0.5f * cd + 0.5f * emd;
    }
}

extern "C" void kernel_launch(void* const* d_in, const int* in_sizes, int n_in,
                              void* d_out, int out_size, void* d_ws, size_t ws_size,
                              hipStream_t stream)
{
    const float* Xtrue = (const float*)d_in[0];   // y_true: rows of D
    const float* Ypred = (const float*)d_in[1];   // y_pred: cols of D

    float* F    = (float*)d_ws;                   // [16][2048]
    float* G    = F + BATCH * NPTS;               // [16][2048]
    float* part = G + BATCH * NPTS;               // [2048]
    v4f*  Xg    = (v4f*)(part + 2 * GRID_X * BATCH);   // 16B-aligned (offset 270336)
    v4f*  Yg    = Xg + (size_t)BATCH * NPTS;
    v4f*  FoldX = Yg + (size_t)BATCH * NPTS;
    v4f*  FoldY = FoldX + (size_t)BATCH * NPTS;

    pack_geo<<<dim3(NPAIR / 256, BATCH), dim3(256), 0, stream>>>(Xtrue, Ypred, Xg, Yg);

    dim3 grid(GRID_X, BATCH), blk(256);
    chamfer_b<<<grid, blk, 0, stream>>>(Yg, Xg, part + GRID_X * BATCH);

    // iter 0: f-update stages pristine Yg (pot=0) and emits chamfer dir-A
    sink_step<<<grid, blk, 0, stream>>>(Xg, Yg, F, FoldX, part);
    sink_step<<<grid, blk, 0, stream>>>(Yg, FoldX, G, FoldY, nullptr);
    for (int it = 1; it < ITERS; ++it) {
        sink_step<<<grid, blk, 0, stream>>>(Xg, FoldY, F, FoldX, nullptr);
        sink_step<<<grid, blk, 0, stream>>>(Yg, FoldX, G, FoldY, nullptr);
    }
    finalize<<<dim3(BATCH), blk, 0, stream>>>(F, G, part, (float*)d_out);
}